// Round 4
// baseline (272.953 us; speedup 1.0000x reference)
//
#include <hip/hip_runtime.h>
#include <math.h>

#define Bb 8
#define Cc 64
#define Nn 256
#define FD 128
#define SEGS 4
#define ROWS 64          // rows per block
#define TILE (Nn * FD)   // 32768 floats per (b,c)
#define NBLK (Bb * Cc * SEGS)   // 2048
#define SPIN_MAX 2000000        // bounded spin: fail loudly, never hang

typedef float floatx4 __attribute__((ext_vector_type(4)));

// ---------------------------------------------------------------------------
// Single-launch channel-pipelined kernel. 2048 blocks x 256 threads.
// Block = (c, b, seg) with c as the SLOW index: channel c's 32 blocks
// (8 b x 4 seg) are contiguous in dispatch order, so they are co-resident
// together and complete together.
//
// Produce: identical math to the proven s1 — per-row mask logit dh
//   (5-step half-wave butterfly + LDS broadcast), mask-folded register
//   partials, block reduce -> 6 masked partials (+2 source dots on seg0)
//   stored to bpart[blk*8..]. Row mask stays in LDS (no global round trip).
// Sync: release fetch_add on done[c]; acquire spin until done[c]==32.
//   Only channel-local — no global barrier. Channels pipeline: while late
//   channels produce, early channels consume (overlapped read+write BW).
// Consume: read channel c's 32 records (1 KB contiguous), finalize softmax
//   weights + BN scale/shift redundantly (uniform, cheap), then
//   elu(fma(h, w*scale, shift)) over the block's OWN slice — the 32 KB it
//   just produced from, L1/L2-warm on the same CU/XCD. Nontemporal stores.
// ---------------------------------------------------------------------------
__global__ __launch_bounds__(256) void pipe(
    const float* __restrict__ h, const float* __restrict__ op,
    const float* __restrict__ opS, const float* __restrict__ opQ,
    const float* __restrict__ gamma, const float* __restrict__ beta,
    float* __restrict__ out, float* __restrict__ bpart,
    unsigned int* __restrict__ done) {
  const int blk = blockIdx.x;
  const int c = blk >> 5, b = (blk >> 2) & (Bb - 1), seg = blk & 3;
  const int bc = b * Cc + c;
  const float* __restrict__ tile = h + (size_t)bc * TILE;
  const int tid = threadIdx.x, lane = tid & 63, wv = tid >> 6;
  const int hw = tid >> 5, hl = tid & 31;

  __shared__ float s_dh[ROWS];
  __shared__ float s_red[4][6];
  __shared__ float s_cs;
  __shared__ float s_ssq[2];
  __shared__ unsigned long long s_mask;     // this block's 64-row mask
  __shared__ float s_S[Bb], s_SS[Bb], s_ws[2];
  __shared__ float s_a[ROWS];

  // ---- produce: wave 0 does the source-row dots ----
  if (wv == 0) {
    const float* __restrict__ opc = op + c * 2 * FD;
    const float a = tile[lane], bb2 = tile[lane + 64];
    float cs = a * opc[lane] + bb2 * opc[lane + 64];
    float ssv = 0.0f, qqv = 0.0f;
    if (seg == 0) {
      const float* __restrict__ opSc = opS + c * 2 * FD + FD;
      const float* __restrict__ opQc = opQ + c * 2 * FD + FD;
      ssv = a * opSc[lane] + bb2 * opSc[lane + 64];
      qqv = a * opQc[lane] + bb2 * opQc[lane + 64];
    }
#pragma unroll
    for (int off = 32; off >= 1; off >>= 1) {
      cs  += __shfl_xor(cs,  off, 64);
      ssv += __shfl_xor(ssv, off, 64);
      qqv += __shfl_xor(qqv, off, 64);
    }
    if (lane == 0) { s_cs = cs; s_ssq[0] = ssv; s_ssq[1] = qqv; }
  }

  const float4 oH = ((const float4*)(op  + c * 2 * FD + FD))[hl];
  const float4 oS = ((const float4*)(opS + c * 2 * FD))[hl];
  const float4 oQ = ((const float4*)(opQ + c * 2 * FD))[hl];

  float dsp[8], dqp[8], rsp[8], rssp[8];

  // 8 half-waves x 8 rows = 64 rows; one float4 per half-wave-lane per row.
#pragma unroll
  for (int i = 0; i < 8; ++i) {
    const int nl = hw * 8 + i;
    const float4 v = ((const float4*)(tile + (size_t)(seg * ROWS + nl) * FD))[hl];
    float dh = v.x * oH.x + v.y * oH.y + v.z * oH.z + v.w * oH.w;
    dsp[i]  = v.x * oS.x + v.y * oS.y + v.z * oS.z + v.w * oS.w;
    dqp[i]  = v.x * oQ.x + v.y * oQ.y + v.z * oQ.z + v.w * oQ.w;
    rsp[i]  = v.x + v.y + v.z + v.w;
    rssp[i] = v.x * v.x + v.y * v.y + v.z * v.z + v.w * v.w;
#pragma unroll
    for (int off = 16; off >= 1; off >>= 1) dh += __shfl_xor(dh, off, 64);
    if (hl == 0) s_dh[nl] = dh;
  }
  __syncthreads();

  const float cs = s_cs;

  // row mask -> LDS only
  if (wv == 0) {
    const bool m = (s_dh[lane] + cs) >= 0.0f;
    const unsigned long long bits = __ballot(m);
    if (lane == 0) s_mask = bits;
  }

  // mask-weighted lane-local accumulation over this lane's 8 rows
  float a_ds = 0, a_dq = 0, a_rsm = 0, a_rsq = 0, a_rssm = 0, a_rssq = 0;
#pragma unroll
  for (int i = 0; i < 8; ++i) {
    const bool m = (s_dh[hw * 8 + i] + cs) >= 0.0f;
    a_ds   += m ? dsp[i]  : 0.0f;
    a_dq   += m ? 0.0f    : dqp[i];
    a_rsm  += m ? rsp[i]  : 0.0f;
    a_rsq  += m ? 0.0f    : rsp[i];
    a_rssm += m ? rssp[i] : 0.0f;
    a_rssq += m ? 0.0f    : rssp[i];
  }
#pragma unroll
  for (int off = 32; off >= 1; off >>= 1) {
    a_ds   += __shfl_xor(a_ds,   off, 64);
    a_dq   += __shfl_xor(a_dq,   off, 64);
    a_rsm  += __shfl_xor(a_rsm,  off, 64);
    a_rsq  += __shfl_xor(a_rsq,  off, 64);
    a_rssm += __shfl_xor(a_rssm, off, 64);
    a_rssq += __shfl_xor(a_rssq, off, 64);
  }
  if (lane == 0) {
    s_red[wv][0] = a_ds;  s_red[wv][1] = a_dq;
    s_red[wv][2] = a_rsm; s_red[wv][3] = a_rsq;
    s_red[wv][4] = a_rssm; s_red[wv][5] = a_rssq;
  }
  __syncthreads();
  if (tid < 6) {
    bpart[(size_t)blk * 8 + tid] =
        s_red[0][tid] + s_red[1][tid] + s_red[2][tid] + s_red[3][tid];
  }
  if (seg == 0 && tid >= 6 && tid < 8) {
    bpart[(size_t)blk * 8 + tid] = s_ssq[tid - 6];
  }

  // ---- channel-local sync: release arrival, acquire spin to 32 ----
  __syncthreads();   // all bpart stores drained (vmcnt(0) before s_barrier)
  if (tid == 0) {
    __hip_atomic_fetch_add(&done[c], 1u, __ATOMIC_RELEASE,
                           __HIP_MEMORY_SCOPE_AGENT);
    int it = 0;
    while (__hip_atomic_load(&done[c], __ATOMIC_ACQUIRE,
                             __HIP_MEMORY_SCOPE_AGENT) < 32u) {
      if (++it > SPIN_MAX) break;  // scheduling pathology: fail loudly
      __builtin_amdgcn_s_sleep(2);
    }
  }
  __syncthreads();

  // ---- consume: channel c's 32 records (contiguous 1 KB) ----
  const int bb = hw;   // 8 half-waves -> 8 batch entries
  float aj = 0.0f;
  if (hl < 6) {
#pragma unroll
    for (int k = 0; k < SEGS; ++k)
      aj += bpart[(size_t)(c * 32 + bb * 4 + k) * 8 + hl];
  } else if (hl < 8) {
    aj = bpart[(size_t)(c * 32 + bb * 4) * 8 + hl];   // seg0 source dots
  }
  const int base = lane & 32;
  const float a0 = __shfl(aj, base + 0, 64), a1 = __shfl(aj, base + 1, 64);
  const float a2 = __shfl(aj, base + 2, 64), a3 = __shfl(aj, base + 3, 64);
  const float a4 = __shfl(aj, base + 4, 64), a5 = __shfl(aj, base + 5, 64);
  const float ss = __shfl(aj, base + 6, 64), qq = __shfl(aj, base + 7, 64);

  const float sa = a0 * (1.0f / Nn) + ss;
  const float qa = a1 * (1.0f / Nn) + qq;
  const float mx = fmaxf(sa, qa);
  const float es = __expf(sa - mx), eq = __expf(qa - mx);
  const float inv = 1.0f / (es + eq);
  const float w_s = es * inv, w_q = eq * inv;
  if (hl == 0) {
    s_S[bb]  = w_s * a2 + w_q * a3;
    s_SS[bb] = w_s * w_s * a4 + w_q * w_q * a5;
    if (bb == b) { s_ws[0] = w_s; s_ws[1] = w_q; }
  }
  __syncthreads();

  float S = 0.0f, SS = 0.0f;
#pragma unroll
  for (int k = 0; k < Bb; ++k) { S += s_S[k]; SS += s_SS[k]; }
  const float invcnt = 1.0f / (float)(Bb * Nn * FD);
  const float mean = S * invcnt;
  const float var  = SS * invcnt - mean * mean;
  const float scale = gamma[c] * rsqrtf(var + 1e-5f);
  const float shift = beta[c] - mean * scale;

  if (tid < ROWS) {
    const float w = ((s_mask >> tid) & 1ull) ? s_ws[0] : s_ws[1];
    s_a[tid] = w * scale;
  }
  __syncthreads();

  // elementwise over this block's OWN (cache-warm) 32 KB slice
  const float4* __restrict__ h4 = (const float4*)tile + seg * 2048;
  floatx4* __restrict__ o4 = (floatx4*)(out + (size_t)bc * TILE) + seg * 2048;
#pragma unroll
  for (int k = 0; k < 8; ++k) {
    const int idx = k * 256 + tid;
    const float a = s_a[idx >> 5];   // 32 float4 per row -> broadcast per 32 lanes
    const float4 v = h4[idx];
    floatx4 r;
    r.x = fmaf(v.x, a, shift);
    r.y = fmaf(v.y, a, shift);
    r.z = fmaf(v.z, a, shift);
    r.w = fmaf(v.w, a, shift);
    r.x = r.x > 0.0f ? r.x : __expf(r.x) - 1.0f;
    r.y = r.y > 0.0f ? r.y : __expf(r.y) - 1.0f;
    r.z = r.z > 0.0f ? r.z : __expf(r.z) - 1.0f;
    r.w = r.w > 0.0f ? r.w : __expf(r.w) - 1.0f;
    __builtin_nontemporal_store(r, &o4[idx]);
  }
}

extern "C" void kernel_launch(void* const* d_in, const int* in_sizes, int n_in,
                              void* d_out, int out_size, void* d_ws, size_t ws_size,
                              hipStream_t stream) {
  const float* h     = (const float*)d_in[0];
  const float* op    = (const float*)d_in[1];
  const float* opS   = (const float*)d_in[2];
  const float* opQ   = (const float*)d_in[3];
  const float* gamma = (const float*)d_in[4];
  const float* beta  = (const float*)d_in[5];
  float* out = (float*)d_out;

  float* bpart = (float*)d_ws;                               // 2048*8 f32 = 64 KB
  unsigned int* done = (unsigned int*)((char*)d_ws + 65536); // 64 u32

  hipMemsetAsync(done, 0, Cc * sizeof(unsigned int), stream);
  pipe<<<NBLK, 256, 0, stream>>>(h, op, opS, opQ, gamma, beta, out,
                                 bpart, done);
}

// Round 5
// 264.500 us; speedup vs baseline: 1.0320x; 1.0320x over previous
//
#include <hip/hip_runtime.h>
#include <math.h>

#define Bb 8
#define Cc 64
#define Nn 256
#define FD 128
#define SEGS 4
#define ROWS 64          // rows per block
#define TILE (Nn * FD)   // 32768 floats per (b,c)
#define NBLK (Bb * Cc * SEGS)   // 2048
#define SPIN_MAX 2000000        // bounded spin: fail loudly, never hang

typedef float floatx4 __attribute__((ext_vector_type(4)));

// ---------------------------------------------------------------------------
// Single-launch channel-pipelined kernel. 2048 blocks x 256 threads.
// Block = (c, b, seg) with c as the SLOW index: channel c's 32 blocks
// (8 b x 4 seg) are contiguous in dispatch order.
//
// __launch_bounds__(256, 4): min 4 waves/EU -> VGPR cap 128. Round 4 showed
// that WITHOUT this the compiler targets 8 blocks/CU, allocates 32 VGPRs,
// and spills/remats the 32-float per-lane accumulator state (165 us, VALU
// 5.6%, HBM 0.8 TB/s). Round 2's identical produce code at (256,2) compiled
// to a clean 92 VGPR — the hint is the knob.
//
// Produce: per-row mask logit dh (5-step half-wave butterfly + LDS
//   broadcast), mask-folded register partials, block reduce -> 6 masked
//   partials (+2 source dots on seg0) stored to bpart[blk*8..]. Row mask
//   stays in LDS.
// Sync: release fetch_add on done[c]; acquire spin until done[c]==32.
//   Channel-local only — channels pipeline, no global barrier.
// Consume: read channel c's 32 records (1 KB contiguous), finalize softmax
//   weights + BN scale/shift redundantly, then elu(fma(h, w*scale, shift))
//   over the block's OWN (L1/L2-warm) 32 KB slice, nontemporal stores.
// ---------------------------------------------------------------------------
__global__ __launch_bounds__(256, 4) void pipe(
    const float* __restrict__ h, const float* __restrict__ op,
    const float* __restrict__ opS, const float* __restrict__ opQ,
    const float* __restrict__ gamma, const float* __restrict__ beta,
    float* __restrict__ out, float* __restrict__ bpart,
    unsigned int* __restrict__ done) {
  const int blk = blockIdx.x;
  const int c = blk >> 5, b = (blk >> 2) & (Bb - 1), seg = blk & 3;
  const int bc = b * Cc + c;
  const float* __restrict__ tile = h + (size_t)bc * TILE;
  const int tid = threadIdx.x, lane = tid & 63, wv = tid >> 6;
  const int hw = tid >> 5, hl = tid & 31;

  __shared__ float s_dh[ROWS];
  __shared__ float s_red[4][6];
  __shared__ float s_cs;
  __shared__ float s_ssq[2];
  __shared__ unsigned long long s_mask;     // this block's 64-row mask
  __shared__ float s_S[Bb], s_SS[Bb], s_ws[2];
  __shared__ float s_a[ROWS];

  // ---- produce: wave 0 does the source-row dots ----
  if (wv == 0) {
    const float* __restrict__ opc = op + c * 2 * FD;
    const float a = tile[lane], bb2 = tile[lane + 64];
    float cs = a * opc[lane] + bb2 * opc[lane + 64];
    float ssv = 0.0f, qqv = 0.0f;
    if (seg == 0) {
      const float* __restrict__ opSc = opS + c * 2 * FD + FD;
      const float* __restrict__ opQc = opQ + c * 2 * FD + FD;
      ssv = a * opSc[lane] + bb2 * opSc[lane + 64];
      qqv = a * opQc[lane] + bb2 * opQc[lane + 64];
    }
#pragma unroll
    for (int off = 32; off >= 1; off >>= 1) {
      cs  += __shfl_xor(cs,  off, 64);
      ssv += __shfl_xor(ssv, off, 64);
      qqv += __shfl_xor(qqv, off, 64);
    }
    if (lane == 0) { s_cs = cs; s_ssq[0] = ssv; s_ssq[1] = qqv; }
  }

  const float4 oH = ((const float4*)(op  + c * 2 * FD + FD))[hl];
  const float4 oS = ((const float4*)(opS + c * 2 * FD))[hl];
  const float4 oQ = ((const float4*)(opQ + c * 2 * FD))[hl];

  float dsp[8], dqp[8], rsp[8], rssp[8];

  // 8 half-waves x 8 rows = 64 rows; one float4 per half-wave-lane per row.
#pragma unroll
  for (int i = 0; i < 8; ++i) {
    const int nl = hw * 8 + i;
    const float4 v = ((const float4*)(tile + (size_t)(seg * ROWS + nl) * FD))[hl];
    float dh = v.x * oH.x + v.y * oH.y + v.z * oH.z + v.w * oH.w;
    dsp[i]  = v.x * oS.x + v.y * oS.y + v.z * oS.z + v.w * oS.w;
    dqp[i]  = v.x * oQ.x + v.y * oQ.y + v.z * oQ.z + v.w * oQ.w;
    rsp[i]  = v.x + v.y + v.z + v.w;
    rssp[i] = v.x * v.x + v.y * v.y + v.z * v.z + v.w * v.w;
#pragma unroll
    for (int off = 16; off >= 1; off >>= 1) dh += __shfl_xor(dh, off, 64);
    if (hl == 0) s_dh[nl] = dh;
  }
  __syncthreads();

  const float cs = s_cs;

  // row mask -> LDS only
  if (wv == 0) {
    const bool m = (s_dh[lane] + cs) >= 0.0f;
    const unsigned long long bits = __ballot(m);
    if (lane == 0) s_mask = bits;
  }

  // mask-weighted lane-local accumulation over this lane's 8 rows
  float a_ds = 0, a_dq = 0, a_rsm = 0, a_rsq = 0, a_rssm = 0, a_rssq = 0;
#pragma unroll
  for (int i = 0; i < 8; ++i) {
    const bool m = (s_dh[hw * 8 + i] + cs) >= 0.0f;
    a_ds   += m ? dsp[i]  : 0.0f;
    a_dq   += m ? 0.0f    : dqp[i];
    a_rsm  += m ? rsp[i]  : 0.0f;
    a_rsq  += m ? 0.0f    : rsp[i];
    a_rssm += m ? rssp[i] : 0.0f;
    a_rssq += m ? 0.0f    : rssp[i];
  }
#pragma unroll
  for (int off = 32; off >= 1; off >>= 1) {
    a_ds   += __shfl_xor(a_ds,   off, 64);
    a_dq   += __shfl_xor(a_dq,   off, 64);
    a_rsm  += __shfl_xor(a_rsm,  off, 64);
    a_rsq  += __shfl_xor(a_rsq,  off, 64);
    a_rssm += __shfl_xor(a_rssm, off, 64);
    a_rssq += __shfl_xor(a_rssq, off, 64);
  }
  if (lane == 0) {
    s_red[wv][0] = a_ds;  s_red[wv][1] = a_dq;
    s_red[wv][2] = a_rsm; s_red[wv][3] = a_rsq;
    s_red[wv][4] = a_rssm; s_red[wv][5] = a_rssq;
  }
  __syncthreads();
  if (tid < 6) {
    bpart[(size_t)blk * 8 + tid] =
        s_red[0][tid] + s_red[1][tid] + s_red[2][tid] + s_red[3][tid];
  }
  if (seg == 0 && tid >= 6 && tid < 8) {
    bpart[(size_t)blk * 8 + tid] = s_ssq[tid - 6];
  }

  // ---- channel-local sync: release arrival, acquire spin to 32 ----
  __syncthreads();   // all bpart stores drained (vmcnt(0) before s_barrier)
  if (tid == 0) {
    __hip_atomic_fetch_add(&done[c], 1u, __ATOMIC_RELEASE,
                           __HIP_MEMORY_SCOPE_AGENT);
    int it = 0;
    while (__hip_atomic_load(&done[c], __ATOMIC_ACQUIRE,
                             __HIP_MEMORY_SCOPE_AGENT) < 32u) {
      if (++it > SPIN_MAX) break;  // scheduling pathology: fail loudly
      __builtin_amdgcn_s_sleep(2);
    }
  }
  __syncthreads();

  // ---- consume: channel c's 32 records (contiguous 1 KB) ----
  const int bb = hw;   // 8 half-waves -> 8 batch entries
  float aj = 0.0f;
  if (hl < 6) {
#pragma unroll
    for (int k = 0; k < SEGS; ++k)
      aj += bpart[(size_t)(c * 32 + bb * 4 + k) * 8 + hl];
  } else if (hl < 8) {
    aj = bpart[(size_t)(c * 32 + bb * 4) * 8 + hl];   // seg0 source dots
  }
  const int base = lane & 32;
  const float a0 = __shfl(aj, base + 0, 64), a1 = __shfl(aj, base + 1, 64);
  const float a2 = __shfl(aj, base + 2, 64), a3 = __shfl(aj, base + 3, 64);
  const float a4 = __shfl(aj, base + 4, 64), a5 = __shfl(aj, base + 5, 64);
  const float ss = __shfl(aj, base + 6, 64), qq = __shfl(aj, base + 7, 64);

  const float sa = a0 * (1.0f / Nn) + ss;
  const float qa = a1 * (1.0f / Nn) + qq;
  const float mx = fmaxf(sa, qa);
  const float es = __expf(sa - mx), eq = __expf(qa - mx);
  const float inv = 1.0f / (es + eq);
  const float w_s = es * inv, w_q = eq * inv;
  if (hl == 0) {
    s_S[bb]  = w_s * a2 + w_q * a3;
    s_SS[bb] = w_s * w_s * a4 + w_q * w_q * a5;
    if (bb == b) { s_ws[0] = w_s; s_ws[1] = w_q; }
  }
  __syncthreads();

  float S = 0.0f, SS = 0.0f;
#pragma unroll
  for (int k = 0; k < Bb; ++k) { S += s_S[k]; SS += s_SS[k]; }
  const float invcnt = 1.0f / (float)(Bb * Nn * FD);
  const float mean = S * invcnt;
  const float var  = SS * invcnt - mean * mean;
  const float scale = gamma[c] * rsqrtf(var + 1e-5f);
  const float shift = beta[c] - mean * scale;

  if (tid < ROWS) {
    const float w = ((s_mask >> tid) & 1ull) ? s_ws[0] : s_ws[1];
    s_a[tid] = w * scale;
  }
  __syncthreads();

  // elementwise over this block's OWN (cache-warm) 32 KB slice
  const float4* __restrict__ h4 = (const float4*)tile + seg * 2048;
  floatx4* __restrict__ o4 = (floatx4*)(out + (size_t)bc * TILE) + seg * 2048;
#pragma unroll
  for (int k = 0; k < 8; ++k) {
    const int idx = k * 256 + tid;
    const float a = s_a[idx >> 5];   // 32 float4 per row -> broadcast per 32 lanes
    const float4 v = h4[idx];
    floatx4 r;
    r.x = fmaf(v.x, a, shift);
    r.y = fmaf(v.y, a, shift);
    r.z = fmaf(v.z, a, shift);
    r.w = fmaf(v.w, a, shift);
    r.x = r.x > 0.0f ? r.x : __expf(r.x) - 1.0f;
    r.y = r.y > 0.0f ? r.y : __expf(r.y) - 1.0f;
    r.z = r.z > 0.0f ? r.z : __expf(r.z) - 1.0f;
    r.w = r.w > 0.0f ? r.w : __expf(r.w) - 1.0f;
    __builtin_nontemporal_store(r, &o4[idx]);
  }
}

extern "C" void kernel_launch(void* const* d_in, const int* in_sizes, int n_in,
                              void* d_out, int out_size, void* d_ws, size_t ws_size,
                              hipStream_t stream) {
  const float* h     = (const float*)d_in[0];
  const float* op    = (const float*)d_in[1];
  const float* opS   = (const float*)d_in[2];
  const float* opQ   = (const float*)d_in[3];
  const float* gamma = (const float*)d_in[4];
  const float* beta  = (const float*)d_in[5];
  float* out = (float*)d_out;

  float* bpart = (float*)d_ws;                               // 2048*8 f32 = 64 KB
  unsigned int* done = (unsigned int*)((char*)d_ws + 65536); // 64 u32

  hipMemsetAsync(done, 0, Cc * sizeof(unsigned int), stream);
  pipe<<<NBLK, 256, 0, stream>>>(h, op, opS, opQ, gamma, beta, out,
                                 bpart, done);
}

// Round 6
// 133.448 us; speedup vs baseline: 2.0454x; 1.9820x over previous
//
#include <hip/hip_runtime.h>
#include <math.h>

#define Bb 8
#define Cc 64
#define Nn 256
#define FD 128
#define SEGS 4
#define ROWS 64          // rows per block
#define TILE (Nn * FD)   // 32768 floats per (b,c)

typedef float floatx4 __attribute__((ext_vector_type(4)));

// ---------------------------------------------------------------------------
// s1: one block per (bc, seg) — 64 rows, single pass over its 32 KB slice.
//
// __launch_bounds__(256, 2): CRITICAL. With the default (or min-waves=4),
// hipcc's occupancy heuristic shrinks the kernel to 32 VGPRs and
// rematerializes the 32 per-lane accumulator floats by RE-LOADING the
// float4 tile data in the mask-fold loop (rounds 4/5: VALUBusy 5.3%,
// HBM 0.75 TB/s, 176 us — latency-bound serial chain, zero ILP).
// min-waves=2 relaxes the heuristic; the identical loop in round 2
// compiled to a clean 92 VGPR with accumulators resident.
//
// Only the mask logit dh is reduced per-row; dotS/dotQ/rowsum/rowsumsq are
// kept as per-lane register partials and folded with the mask AFTER the
// barrier, then reduced once block-wide (6 values).
// seg==0 blocks additionally compute the source-row dots ss,qq once per
// (b,c) and store them in bpart slots 6,7.
// Emits: 64-bit row mask + 6 masked block partials (+2 source dots on seg0)
// ---------------------------------------------------------------------------
__global__ __launch_bounds__(256, 2) void s1(
    const float* __restrict__ h, const float* __restrict__ op,
    const float* __restrict__ opS, const float* __restrict__ opQ,
    unsigned long long* __restrict__ maskbuf, float* __restrict__ bpart) {
  const int blk = blockIdx.x;
  const int bc = blk >> 2, seg = blk & 3;
  const int c = bc & (Cc - 1);
  const float* __restrict__ tile = h + (size_t)bc * TILE;
  const int tid = threadIdx.x, lane = tid & 63, wv = tid >> 6;
  const int hw = tid >> 5, hl = tid & 31;

  __shared__ float s_dh[ROWS];
  __shared__ float s_red[4][6];
  __shared__ float s_cs;
  __shared__ float s_ssq[2];

  // wave 0: const_src = <source_row, op[c][0:FD]> -> LDS for all waves.
  // seg==0 blocks also produce the source-row dots for opS/opQ (slots 6,7).
  if (wv == 0) {
    const float* __restrict__ opc = op + c * 2 * FD;
    const float a = tile[lane], b = tile[lane + 64];
    float cs = a * opc[lane] + b * opc[lane + 64];
    float ssv = 0.0f, qqv = 0.0f;
    if (seg == 0) {
      const float* __restrict__ opSc = opS + c * 2 * FD + FD;
      const float* __restrict__ opQc = opQ + c * 2 * FD + FD;
      ssv = a * opSc[lane] + b * opSc[lane + 64];
      qqv = a * opQc[lane] + b * opQc[lane + 64];
    }
#pragma unroll
    for (int off = 32; off >= 1; off >>= 1) {
      cs  += __shfl_xor(cs,  off, 64);
      ssv += __shfl_xor(ssv, off, 64);
      qqv += __shfl_xor(qqv, off, 64);
    }
    if (lane == 0) { s_cs = cs; s_ssq[0] = ssv; s_ssq[1] = qqv; }
  }

  const float4 oH = ((const float4*)(op  + c * 2 * FD + FD))[hl];
  const float4 oS = ((const float4*)(opS + c * 2 * FD))[hl];
  const float4 oQ = ((const float4*)(opQ + c * 2 * FD))[hl];

  float dsp[8], dqp[8], rsp[8], rssp[8];

  // 8 half-waves x 8 rows = 64 rows; one float4 per half-wave-lane per row.
  // Per iteration only dh is butterfly-reduced (5 steps, both halves).
#pragma unroll
  for (int i = 0; i < 8; ++i) {
    const int nl = hw * 8 + i;
    const float4 v = ((const float4*)(tile + (size_t)(seg * ROWS + nl) * FD))[hl];
    float dh = v.x * oH.x + v.y * oH.y + v.z * oH.z + v.w * oH.w;
    dsp[i]  = v.x * oS.x + v.y * oS.y + v.z * oS.z + v.w * oS.w;
    dqp[i]  = v.x * oQ.x + v.y * oQ.y + v.z * oQ.z + v.w * oQ.w;
    rsp[i]  = v.x + v.y + v.z + v.w;
    rssp[i] = v.x * v.x + v.y * v.y + v.z * v.z + v.w * v.w;
#pragma unroll
    for (int off = 16; off >= 1; off >>= 1) dh += __shfl_xor(dh, off, 64);
    if (hl == 0) s_dh[nl] = dh;
  }
  __syncthreads();

  const float cs = s_cs;

  // ballot mask (wave 0 handles all 64 rows)
  if (wv == 0) {
    const bool m = (s_dh[lane] + cs) >= 0.0f;
    const unsigned long long bits = __ballot(m);
    if (lane == 0) maskbuf[blk] = bits;
  }

  // mask-weighted lane-local accumulation over this lane's 8 rows
  float a_ds = 0, a_dq = 0, a_rsm = 0, a_rsq = 0, a_rssm = 0, a_rssq = 0;
#pragma unroll
  for (int i = 0; i < 8; ++i) {
    const bool m = (s_dh[hw * 8 + i] + cs) >= 0.0f;
    a_ds   += m ? dsp[i]  : 0.0f;
    a_dq   += m ? 0.0f    : dqp[i];
    a_rsm  += m ? rsp[i]  : 0.0f;
    a_rsq  += m ? 0.0f    : rsp[i];
    a_rssm += m ? rssp[i] : 0.0f;
    a_rssq += m ? 0.0f    : rssp[i];
  }
  // one full-wave butterfly (6 steps x 6 values)
#pragma unroll
  for (int off = 32; off >= 1; off >>= 1) {
    a_ds   += __shfl_xor(a_ds,   off, 64);
    a_dq   += __shfl_xor(a_dq,   off, 64);
    a_rsm  += __shfl_xor(a_rsm,  off, 64);
    a_rsq  += __shfl_xor(a_rsq,  off, 64);
    a_rssm += __shfl_xor(a_rssm, off, 64);
    a_rssq += __shfl_xor(a_rssq, off, 64);
  }
  if (lane == 0) {
    s_red[wv][0] = a_ds;  s_red[wv][1] = a_dq;
    s_red[wv][2] = a_rsm; s_red[wv][3] = a_rsq;
    s_red[wv][4] = a_rssm; s_red[wv][5] = a_rssq;
  }
  __syncthreads();
  if (tid < 6) {
    bpart[(size_t)blk * 8 + tid] =
        s_red[0][tid] + s_red[1][tid] + s_red[2][tid] + s_red[3][tid];
  }
  if (seg == 0 && tid >= 6 && tid < 8) {
    bpart[(size_t)blk * 8 + tid] = s_ssq[tid - 6];
  }
}

// ---------------------------------------------------------------------------
// s2f: fused finalize + elementwise. One block per (bc, seg).
// Preamble reads everything from bpart (8 slots: 6 seg-summed partials +
// 2 source dots from seg0). Then per-b softmax weights + channel BN
// scale/shift, and elu(fma(h, w*scale, shift)) over the 32 KB slice
// (L3-hot re-read), nontemporal stores for the write-once output.
// ---------------------------------------------------------------------------
__global__ __launch_bounds__(256) void s2f(
    const float* __restrict__ h, const unsigned long long* __restrict__ maskbuf,
    const float* __restrict__ bpart, const float* __restrict__ gamma,
    const float* __restrict__ beta, float* __restrict__ out) {
  const int blk = blockIdx.x, bc = blk >> 2, seg = blk & 3;
  const int c = bc & (Cc - 1), bmine = bc >> 6;
  const int tid = threadIdx.x, lane = tid & 63, hw = tid >> 5, hl = tid & 31;
  __shared__ float s_S[Bb], s_SS[Bb], s_ws[2 * Bb];
  __shared__ float s_a[ROWS];

  const int b = hw;                    // 8 half-waves -> 8 batch entries
  const int bcb = b * Cc + c;

  // combine the 4 seg-partials (lanes hl<6, one j each); hl==6,7 read the
  // seg0-only source dots.
  float aj = 0.0f;
  if (hl < 6) {
#pragma unroll
    for (int k = 0; k < SEGS; ++k)
      aj += bpart[(size_t)(bcb * SEGS + k) * 8 + hl];
  } else if (hl < 8) {
    aj = bpart[(size_t)(bcb * SEGS) * 8 + hl];
  }
  const int base = lane & 32;
  float a0 = __shfl(aj, base + 0, 64), a1 = __shfl(aj, base + 1, 64);
  float a2 = __shfl(aj, base + 2, 64), a3 = __shfl(aj, base + 3, 64);
  float a4 = __shfl(aj, base + 4, 64), a5 = __shfl(aj, base + 5, 64);
  float ss = __shfl(aj, base + 6, 64), qq = __shfl(aj, base + 7, 64);

  float sa = a0 * (1.0f / Nn) + ss;
  float qa = a1 * (1.0f / Nn) + qq;
  float mx = fmaxf(sa, qa);
  float es = __expf(sa - mx), eq = __expf(qa - mx);
  float inv = 1.0f / (es + eq);
  float w_s = es * inv, w_q = eq * inv;
  if (hl == 0) {
    s_S[b]  = w_s * a2 + w_q * a3;
    s_SS[b] = w_s * w_s * a4 + w_q * w_q * a5;
    s_ws[2 * b] = w_s; s_ws[2 * b + 1] = w_q;
  }
  __syncthreads();

  // channel stats (all threads redundantly, LDS broadcast reads)
  float S = 0.0f, SS = 0.0f;
#pragma unroll
  for (int k = 0; k < Bb; ++k) { S += s_S[k]; SS += s_SS[k]; }
  const float invcnt = 1.0f / (float)(Bb * Nn * FD);
  const float mean = S * invcnt;
  const float var  = SS * invcnt - mean * mean;
  const float scale = gamma[c] * rsqrtf(var + 1e-5f);
  const float shift = beta[c] - mean * scale;

  if (tid < ROWS) {
    const unsigned long long m = maskbuf[blk];
    const float w = ((m >> tid) & 1ull) ? s_ws[2 * bmine] : s_ws[2 * bmine + 1];
    s_a[tid] = w * scale;
  }
  __syncthreads();

  const float4* __restrict__ h4 = (const float4*)(h + (size_t)bc * TILE) + seg * 2048;
  floatx4* __restrict__ o4 = (floatx4*)(out + (size_t)bc * TILE) + seg * 2048;
#pragma unroll
  for (int k = 0; k < 8; ++k) {
    const int idx = k * 256 + tid;
    const float a = s_a[idx >> 5];   // 32 float4 per row -> broadcast per 32 lanes
    float4 v = h4[idx];
    floatx4 r;
    r.x = fmaf(v.x, a, shift);
    r.y = fmaf(v.y, a, shift);
    r.z = fmaf(v.z, a, shift);
    r.w = fmaf(v.w, a, shift);
    r.x = r.x > 0.0f ? r.x : __expf(r.x) - 1.0f;
    r.y = r.y > 0.0f ? r.y : __expf(r.y) - 1.0f;
    r.z = r.z > 0.0f ? r.z : __expf(r.z) - 1.0f;
    r.w = r.w > 0.0f ? r.w : __expf(r.w) - 1.0f;
    __builtin_nontemporal_store(r, &o4[idx]);
  }
}

extern "C" void kernel_launch(void* const* d_in, const int* in_sizes, int n_in,
                              void* d_out, int out_size, void* d_ws, size_t ws_size,
                              hipStream_t stream) {
  const float* h     = (const float*)d_in[0];
  const float* op    = (const float*)d_in[1];
  const float* opS   = (const float*)d_in[2];
  const float* opQ   = (const float*)d_in[3];
  const float* gamma = (const float*)d_in[4];
  const float* beta  = (const float*)d_in[5];
  float* out = (float*)d_out;

  unsigned long long* maskbuf = (unsigned long long*)d_ws;   // 2048 u64 = 16 KB
  float* bpart = (float*)((char*)d_ws + 16384);              // 2048*8 floats = 64 KB

  s1<<<Bb * Cc * SEGS, 256, 0, stream>>>(h, op, opS, opQ, maskbuf, bpart);
  s2f<<<Bb * Cc * SEGS, 256, 0, stream>>>(h, maskbuf, bpart, gamma, beta, out);
}

// Round 8
// 130.998 us; speedup vs baseline: 2.0836x; 1.0187x over previous
//
#include <hip/hip_runtime.h>
#include <math.h>

#define Bb 8
#define Cc 64
#define Nn 256
#define FD 128
#define SEGS 4
#define ROWS 64          // rows per block
#define TILE (Nn * FD)   // 32768 floats per (b,c)

typedef float floatx4 __attribute__((ext_vector_type(4)));

// ---------------------------------------------------------------------------
// s1: one block per (bc, seg) — 64 rows, single pass, in-loop mask fold.
//
// Each half-wave redundantly computes cs = <source_row, op[c][0:F]>
// (L1-hot float4 pair + 5-step butterfly -> all 32 lanes hold the full
// dot). Per row, the dh butterfly leaves the full mask logit in ALL 32
// lanes of the half-wave, so the mask is applied to this lane's
// quarter-row dots immediately — no live arrays, no s_dh broadcast, no
// second pass, one barrier total. Live state ~6 accumulators + 3 operand
// float4s; __launch_bounds__(256,2) guards against the occupancy
// heuristic's 32-VGPR remat pathology (rounds 4/5: 176 us disaster).
//
// seg==0 blocks also compute the source-row dots ss,qq once per (b,c)
// (slots 6,7). Emits: u64 row mask + 6 masked block partials.
// ---------------------------------------------------------------------------
__global__ __launch_bounds__(256, 2) void s1(
    const float* __restrict__ h, const float* __restrict__ op,
    const float* __restrict__ opS, const float* __restrict__ opQ,
    unsigned long long* __restrict__ maskbuf, float* __restrict__ bpart) {
  const int blk = blockIdx.x;
  const int bc = blk >> 2, seg = blk & 3;
  const int c = bc & (Cc - 1);
  const float* __restrict__ tile = h + (size_t)bc * TILE;
  const int tid = threadIdx.x, lane = tid & 63, wv = tid >> 6;
  const int hw = tid >> 5, hl = tid & 31;

  __shared__ unsigned int s_mb[8];   // 8 half-waves x 8 row-mask bits
  __shared__ float s_red[4][6];
  __shared__ float s_ssq[2];

  // per-half-wave redundant source dots (no barrier needed)
  const float4 sv  = ((const float4*)tile)[hl];              // source row
  const float4 ocv = ((const float4*)(op + c * 2 * FD))[hl]; // op[c][0:F]
  float cs = sv.x * ocv.x + sv.y * ocv.y + sv.z * ocv.z + sv.w * ocv.w;
  float ssv = 0.0f, qqv = 0.0f;
  if (seg == 0) {   // softmax source dots, once per (b,c)
    const float4 osv = ((const float4*)(opS + c * 2 * FD + FD))[hl];
    const float4 oqv = ((const float4*)(opQ + c * 2 * FD + FD))[hl];
    ssv = sv.x * osv.x + sv.y * osv.y + sv.z * osv.z + sv.w * osv.w;
    qqv = sv.x * oqv.x + sv.y * oqv.y + sv.z * oqv.z + sv.w * oqv.w;
  }
#pragma unroll
  for (int off = 16; off >= 1; off >>= 1) {
    cs  += __shfl_xor(cs,  off, 64);
    ssv += __shfl_xor(ssv, off, 64);
    qqv += __shfl_xor(qqv, off, 64);
  }
  // all 32 lanes of each half-wave now hold full cs (and ssv/qqv on seg0)

  const float4 oH = ((const float4*)(op  + c * 2 * FD + FD))[hl];
  const float4 oS = ((const float4*)(opS + c * 2 * FD))[hl];
  const float4 oQ = ((const float4*)(opQ + c * 2 * FD))[hl];

  float a_ds = 0, a_dq = 0, a_rsm = 0, a_rsq = 0, a_rssm = 0, a_rssq = 0;
  unsigned int mbits = 0;

  // 8 half-waves x 8 rows = 64 rows; mask folded in-loop (no live arrays).
#pragma unroll
  for (int i = 0; i < 8; ++i) {
    const int nl = hw * 8 + i;
    const float4 v = ((const float4*)(tile + (size_t)(seg * ROWS + nl) * FD))[hl];
    float dh = v.x * oH.x + v.y * oH.y + v.z * oH.z + v.w * oH.w;
    const float ds  = v.x * oS.x + v.y * oS.y + v.z * oS.z + v.w * oS.w;
    const float dq  = v.x * oQ.x + v.y * oQ.y + v.z * oQ.z + v.w * oQ.w;
    const float rs  = v.x + v.y + v.z + v.w;
    const float rss = v.x * v.x + v.y * v.y + v.z * v.z + v.w * v.w;
#pragma unroll
    for (int off = 16; off >= 1; off >>= 1) dh += __shfl_xor(dh, off, 64);
    const bool m = (dh + cs) >= 0.0f;       // full row logit in every lane
    a_ds   += m ? ds  : 0.0f;
    a_dq   += m ? 0.0f : dq;
    a_rsm  += m ? rs  : 0.0f;
    a_rsq  += m ? 0.0f : rs;
    a_rssm += m ? rss : 0.0f;
    a_rssq += m ? 0.0f : rss;
    mbits |= (m ? 1u : 0u) << i;
  }
  if (hl == 0) s_mb[hw] = mbits;

  // block-wide reduction of the 6 masked partials
#pragma unroll
  for (int off = 32; off >= 1; off >>= 1) {
    a_ds   += __shfl_xor(a_ds,   off, 64);
    a_dq   += __shfl_xor(a_dq,   off, 64);
    a_rsm  += __shfl_xor(a_rsm,  off, 64);
    a_rsq  += __shfl_xor(a_rsq,  off, 64);
    a_rssm += __shfl_xor(a_rssm, off, 64);
    a_rssq += __shfl_xor(a_rssq, off, 64);
  }
  if (lane == 0) {
    s_red[wv][0] = a_ds;  s_red[wv][1] = a_dq;
    s_red[wv][2] = a_rsm; s_red[wv][3] = a_rsq;
    s_red[wv][4] = a_rssm; s_red[wv][5] = a_rssq;
  }
  if (seg == 0 && tid == 0) { s_ssq[0] = ssv; s_ssq[1] = qqv; }
  __syncthreads();
  if (tid < 6) {
    bpart[(size_t)blk * 8 + tid] =
        s_red[0][tid] + s_red[1][tid] + s_red[2][tid] + s_red[3][tid];
  }
  if (seg == 0 && tid >= 6 && tid < 8) {
    bpart[(size_t)blk * 8 + tid] = s_ssq[tid - 6];
  }
  if (tid == 0) {
    unsigned long long mk = 0;
#pragma unroll
    for (int k = 0; k < 8; ++k) mk |= (unsigned long long)s_mb[k] << (8 * k);
    maskbuf[blk] = mk;
  }
}

// ---------------------------------------------------------------------------
// s2f: fused finalize + elementwise. One block per (bc, seg). (proven)
// Preamble reads everything from bpart (8 slots: 6 seg-summed partials +
// 2 source dots from seg0). Then per-b softmax weights + channel BN
// scale/shift, and elu(fma(h, w*scale, shift)) over the 32 KB slice
// (L3-hot re-read), nontemporal stores for the write-once output.
// ---------------------------------------------------------------------------
__global__ __launch_bounds__(256) void s2f(
    const float* __restrict__ h, const unsigned long long* __restrict__ maskbuf,
    const float* __restrict__ bpart, const float* __restrict__ gamma,
    const float* __restrict__ beta, float* __restrict__ out) {
  const int blk = blockIdx.x, bc = blk >> 2, seg = blk & 3;
  const int c = bc & (Cc - 1), bmine = bc >> 6;
  const int tid = threadIdx.x, lane = tid & 63, hw = tid >> 5, hl = tid & 31;
  __shared__ float s_S[Bb], s_SS[Bb], s_ws[2 * Bb];
  __shared__ float s_a[ROWS];

  const int b = hw;                    // 8 half-waves -> 8 batch entries
  const int bcb = b * Cc + c;

  // combine the 4 seg-partials (lanes hl<6, one j each); hl==6,7 read the
  // seg0-only source dots.
  float aj = 0.0f;
  if (hl < 6) {
#pragma unroll
    for (int k = 0; k < SEGS; ++k)
      aj += bpart[(size_t)(bcb * SEGS + k) * 8 + hl];
  } else if (hl < 8) {
    aj = bpart[(size_t)(bcb * SEGS) * 8 + hl];
  }
  const int base = lane & 32;
  float a0 = __shfl(aj, base + 0, 64), a1 = __shfl(aj, base + 1, 64);
  float a2 = __shfl(aj, base + 2, 64), a3 = __shfl(aj, base + 3, 64);
  float a4 = __shfl(aj, base + 4, 64), a5 = __shfl(aj, base + 5, 64);
  float ss = __shfl(aj, base + 6, 64), qq = __shfl(aj, base + 7, 64);

  float sa = a0 * (1.0f / Nn) + ss;
  float qa = a1 * (1.0f / Nn) + qq;
  float mx = fmaxf(sa, qa);
  float es = __expf(sa - mx), eq = __expf(qa - mx);
  float inv = 1.0f / (es + eq);
  float w_s = es * inv, w_q = eq * inv;
  if (hl == 0) {
    s_S[b]  = w_s * a2 + w_q * a3;
    s_SS[b] = w_s * w_s * a4 + w_q * w_q * a5;
    s_ws[2 * b] = w_s; s_ws[2 * b + 1] = w_q;
  }
  __syncthreads();

  // channel stats (all threads redundantly, LDS broadcast reads)
  float S = 0.0f, SS = 0.0f;
#pragma unroll
  for (int k = 0; k < Bb; ++k) { S += s_S[k]; SS += s_SS[k]; }
  const float invcnt = 1.0f / (float)(Bb * Nn * FD);
  const float mean = S * invcnt;
  const float var  = SS * invcnt - mean * mean;
  const float scale = gamma[c] * rsqrtf(var + 1e-5f);
  const float shift = beta[c] - mean * scale;

  if (tid < ROWS) {
    const unsigned long long m = maskbuf[blk];
    const float w = ((m >> tid) & 1ull) ? s_ws[2 * bmine] : s_ws[2 * bmine + 1];
    s_a[tid] = w * scale;
  }
  __syncthreads();

  const float4* __restrict__ h4 = (const float4*)(h + (size_t)bc * TILE) + seg * 2048;
  floatx4* __restrict__ o4 = (floatx4*)(out + (size_t)bc * TILE) + seg * 2048;
#pragma unroll
  for (int k = 0; k < 8; ++k) {
    const int idx = k * 256 + tid;
    const float a = s_a[idx >> 5];   // 32 float4 per row -> broadcast per 32 lanes
    float4 v = h4[idx];
    floatx4 r;
    r.x = fmaf(v.x, a, shift);
    r.y = fmaf(v.y, a, shift);
    r.z = fmaf(v.z, a, shift);
    r.w = fmaf(v.w, a, shift);
    r.x = r.x > 0.0f ? r.x : __expf(r.x) - 1.0f;
    r.y = r.y > 0.0f ? r.y : __expf(r.y) - 1.0f;
    r.z = r.z > 0.0f ? r.z : __expf(r.z) - 1.0f;
    r.w = r.w > 0.0f ? r.w : __expf(r.w) - 1.0f;
    __builtin_nontemporal_store(r, &o4[idx]);
  }
}

extern "C" void kernel_launch(void* const* d_in, const int* in_sizes, int n_in,
                              void* d_out, int out_size, void* d_ws, size_t ws_size,
                              hipStream_t stream) {
  const float* h     = (const float*)d_in[0];
  const float* op    = (const float*)d_in[1];
  const float* opS   = (const float*)d_in[2];
  const float* opQ   = (const float*)d_in[3];
  const float* gamma = (const float*)d_in[4];
  const float* beta  = (const float*)d_in[5];
  float* out = (float*)d_out;

  unsigned long long* maskbuf = (unsigned long long*)d_ws;   // 2048 u64 = 16 KB
  float* bpart = (float*)((char*)d_ws + 16384);              // 2048*8 floats = 64 KB

  s1<<<Bb * Cc * SEGS, 256, 0, stream>>>(h, op, opS, opQ, maskbuf, bpart);
  s2f<<<Bb * Cc * SEGS, 256, 0, stream>>>(h, maskbuf, bpart, gamma, beta, out);
}

// Round 10
// 128.763 us; speedup vs baseline: 2.1198x; 1.0174x over previous
//
#include <hip/hip_runtime.h>
#include <math.h>

#define Bb 8
#define Cc 64
#define Nn 256
#define FD 128
#define SEGS 4
#define ROWS 64          // rows per block
#define TILE (Nn * FD)   // 32768 floats per (b,c)

typedef float floatx4 __attribute__((ext_vector_type(4)));

// ---------------------------------------------------------------------------
// s1: one block per (bc, seg) — 64 rows, single pass, in-loop mask fold,
// 16-LANE ROW GROUPS (8 floats/lane).
//
// Why 16-lane groups: round-8's half-wave version spent ~86 wave-ops/KB
// (dots 38, shuffles 20, cndmask 24) ≈ 11.9 B/cyc/CU — barely above the
// 10.2 B/cyc/CU needed to saturate HBM, so s1 was VALU-limited. With 16
// lanes/row the dh butterfly is 4 steps amortized over 4 rows/wave, and
// the query-side accumulators are replaced by unconditional totals
// (rs_tot/rss_tot; s2f reconstructs q = tot - m). ~58 wave-ops/2KB
// (-33%) -> s1 becomes BW-bound.
//
// All 16-lane groups redundantly compute identical cs/ss/qq from the
// (L1-hot) source row — no LDS broadcast, no extra barrier.
// __launch_bounds__(256,2) guards the 32-VGPR remat pathology (r4/r5).
//
// bpart slots: [0]=Σm ds, [1]=Σq dq, [2]=Σm rs, [3]=Σtot rs,
//              [4]=Σm rss, [5]=Σtot rss, ([6],[7]=ss,qq on seg0)
// ---------------------------------------------------------------------------
__global__ __launch_bounds__(256, 2) void s1(
    const float* __restrict__ h, const float* __restrict__ op,
    const float* __restrict__ opS, const float* __restrict__ opQ,
    unsigned long long* __restrict__ maskbuf, float* __restrict__ bpart) {
  const int blk = blockIdx.x;
  const int bc = blk >> 2, seg = blk & 3;
  const int c = bc & (Cc - 1);
  const float* __restrict__ tile = h + (size_t)bc * TILE;
  const int tid = threadIdx.x, lane = tid & 63, wv = tid >> 6;
  const int g = tid >> 4, l16 = tid & 15;   // 16 groups x 16 lanes

  __shared__ unsigned int s_mb[16];  // 16 groups x 4 row-mask bits
  __shared__ float s_red[4][6];

  // every 16-lane group redundantly computes the source-row dots
  const float4 sv0 = ((const float4*)tile)[l16 * 2];
  const float4 sv1 = ((const float4*)tile)[l16 * 2 + 1];
  const float4 oc0 = ((const float4*)(op + c * 2 * FD))[l16 * 2];
  const float4 oc1 = ((const float4*)(op + c * 2 * FD))[l16 * 2 + 1];
  float cs = sv0.x * oc0.x + sv0.y * oc0.y + sv0.z * oc0.z + sv0.w * oc0.w
           + sv1.x * oc1.x + sv1.y * oc1.y + sv1.z * oc1.z + sv1.w * oc1.w;
  float ssv = 0.0f, qqv = 0.0f;
  if (seg == 0) {   // softmax source dots, once per (b,c)
    const float4 os0 = ((const float4*)(opS + c * 2 * FD + FD))[l16 * 2];
    const float4 os1 = ((const float4*)(opS + c * 2 * FD + FD))[l16 * 2 + 1];
    const float4 oq0 = ((const float4*)(opQ + c * 2 * FD + FD))[l16 * 2];
    const float4 oq1 = ((const float4*)(opQ + c * 2 * FD + FD))[l16 * 2 + 1];
    ssv = sv0.x * os0.x + sv0.y * os0.y + sv0.z * os0.z + sv0.w * os0.w
        + sv1.x * os1.x + sv1.y * os1.y + sv1.z * os1.z + sv1.w * os1.w;
    qqv = sv0.x * oq0.x + sv0.y * oq0.y + sv0.z * oq0.z + sv0.w * oq0.w
        + sv1.x * oq1.x + sv1.y * oq1.y + sv1.z * oq1.z + sv1.w * oq1.w;
  }
#pragma unroll
  for (int off = 8; off >= 1; off >>= 1) {   // stays within 16-lane group
    cs  += __shfl_xor(cs,  off, 64);
    ssv += __shfl_xor(ssv, off, 64);
    qqv += __shfl_xor(qqv, off, 64);
  }

  // operand slices: this lane's 8 floats of each operator vector
  const float4 oH0 = ((const float4*)(op  + c * 2 * FD + FD))[l16 * 2];
  const float4 oH1 = ((const float4*)(op  + c * 2 * FD + FD))[l16 * 2 + 1];
  const float4 oS0 = ((const float4*)(opS + c * 2 * FD))[l16 * 2];
  const float4 oS1 = ((const float4*)(opS + c * 2 * FD))[l16 * 2 + 1];
  const float4 oQ0 = ((const float4*)(opQ + c * 2 * FD))[l16 * 2];
  const float4 oQ1 = ((const float4*)(opQ + c * 2 * FD))[l16 * 2 + 1];

  float a_dsm = 0, a_dqq = 0, a_rsm = 0, a_rst = 0, a_rssm = 0, a_rsst = 0;
  unsigned int mbits = 0;

  // 16 groups x 4 rows = 64 rows; each lane covers 8 floats of its row.
#pragma unroll
  for (int i = 0; i < 4; ++i) {
    const int row = g * 4 + i;
    const float* rp = tile + (size_t)(seg * ROWS + row) * FD;
    const float4 v0 = ((const float4*)rp)[l16 * 2];
    const float4 v1 = ((const float4*)rp)[l16 * 2 + 1];
    float dh = v0.x * oH0.x + v0.y * oH0.y + v0.z * oH0.z + v0.w * oH0.w
             + v1.x * oH1.x + v1.y * oH1.y + v1.z * oH1.z + v1.w * oH1.w;
    const float ds = v0.x * oS0.x + v0.y * oS0.y + v0.z * oS0.z + v0.w * oS0.w
                   + v1.x * oS1.x + v1.y * oS1.y + v1.z * oS1.z + v1.w * oS1.w;
    const float dq = v0.x * oQ0.x + v0.y * oQ0.y + v0.z * oQ0.z + v0.w * oQ0.w
                   + v1.x * oQ1.x + v1.y * oQ1.y + v1.z * oQ1.z + v1.w * oQ1.w;
    const float rs  = v0.x + v0.y + v0.z + v0.w + v1.x + v1.y + v1.z + v1.w;
    const float rss = v0.x * v0.x + v0.y * v0.y + v0.z * v0.z + v0.w * v0.w
                    + v1.x * v1.x + v1.y * v1.y + v1.z * v1.z + v1.w * v1.w;
#pragma unroll
    for (int off = 8; off >= 1; off >>= 1) dh += __shfl_xor(dh, off, 64);
    const bool m = (dh + cs) >= 0.0f;       // full row logit in every lane
    a_dsm  += m ? ds  : 0.0f;
    a_dqq  += m ? 0.0f : dq;
    a_rsm  += m ? rs  : 0.0f;
    a_rssm += m ? rss : 0.0f;
    a_rst  += rs;                            // unconditional totals
    a_rsst += rss;
    mbits |= (m ? 1u : 0u) << i;
  }
  if (l16 == 0) s_mb[g] = mbits;

  // block-wide reduction of the 6 partials
#pragma unroll
  for (int off = 32; off >= 1; off >>= 1) {
    a_dsm  += __shfl_xor(a_dsm,  off, 64);
    a_dqq  += __shfl_xor(a_dqq,  off, 64);
    a_rsm  += __shfl_xor(a_rsm,  off, 64);
    a_rst  += __shfl_xor(a_rst,  off, 64);
    a_rssm += __shfl_xor(a_rssm, off, 64);
    a_rsst += __shfl_xor(a_rsst, off, 64);
  }
  if (lane == 0) {
    s_red[wv][0] = a_dsm; s_red[wv][1] = a_dqq;
    s_red[wv][2] = a_rsm; s_red[wv][3] = a_rst;
    s_red[wv][4] = a_rssm; s_red[wv][5] = a_rsst;
  }
  __syncthreads();
  if (tid < 6) {
    bpart[(size_t)blk * 8 + tid] =
        s_red[0][tid] + s_red[1][tid] + s_red[2][tid] + s_red[3][tid];
  }
  // tid 6,7 are in group 0 and hold the full ssv/qqv (group-redundant)
  if (seg == 0 && tid == 6) bpart[(size_t)blk * 8 + 6] = ssv;
  if (seg == 0 && tid == 7) bpart[(size_t)blk * 8 + 7] = qqv;
  if (tid == 0) {
    unsigned long long mk = 0;
#pragma unroll
    for (int k = 0; k < 16; ++k)
      mk |= (unsigned long long)(s_mb[k] & 0xFu) << (4 * k);
    maskbuf[blk] = mk;
  }
}

// ---------------------------------------------------------------------------
// s2f: fused finalize + elementwise. One block per (bc, seg). (proven)
// bpart slots 3,5 are now TOTALS; query-side = total - masked.
// ---------------------------------------------------------------------------
__global__ __launch_bounds__(256) void s2f(
    const float* __restrict__ h, const unsigned long long* __restrict__ maskbuf,
    const float* __restrict__ bpart, const float* __restrict__ gamma,
    const float* __restrict__ beta, float* __restrict__ out) {
  const int blk = blockIdx.x, bc = blk >> 2, seg = blk & 3;
  const int c = bc & (Cc - 1), bmine = bc >> 6;
  const int tid = threadIdx.x, lane = tid & 63, hw = tid >> 5, hl = tid & 31;
  __shared__ float s_S[Bb], s_SS[Bb], s_ws[2 * Bb];
  __shared__ float s_a[ROWS];

  const int b = hw;                    // 8 half-waves -> 8 batch entries
  const int bcb = b * Cc + c;

  // combine the 4 seg-partials (lanes hl<6, one j each); hl==6,7 read the
  // seg0-only source dots.
  float aj = 0.0f;
  if (hl < 6) {
#pragma unroll
    for (int k = 0; k < SEGS; ++k)
      aj += bpart[(size_t)(bcb * SEGS + k) * 8 + hl];
  } else if (hl < 8) {
    aj = bpart[(size_t)(bcb * SEGS) * 8 + hl];
  }
  const int base = lane & 32;
  float a0 = __shfl(aj, base + 0, 64), a1 = __shfl(aj, base + 1, 64);
  float a2 = __shfl(aj, base + 2, 64), a3 = __shfl(aj, base + 3, 64);
  float a4 = __shfl(aj, base + 4, 64), a5 = __shfl(aj, base + 5, 64);
  float ss = __shfl(aj, base + 6, 64), qq = __shfl(aj, base + 7, 64);

  float sa = a0 * (1.0f / Nn) + ss;
  float qa = a1 * (1.0f / Nn) + qq;
  float mx = fmaxf(sa, qa);
  float es = __expf(sa - mx), eq = __expf(qa - mx);
  float inv = 1.0f / (es + eq);
  float w_s = es * inv, w_q = eq * inv;
  if (hl == 0) {
    s_S[b]  = w_s * a2 + w_q * (a3 - a2);              // q = tot - m
    s_SS[b] = w_s * w_s * a4 + w_q * w_q * (a5 - a4);  // q = tot - m
    s_ws[2 * b] = w_s; s_ws[2 * b + 1] = w_q;
  }
  __syncthreads();

  // channel stats (all threads redundantly, LDS broadcast reads)
  float S = 0.0f, SS = 0.0f;
#pragma unroll
  for (int k = 0; k < Bb; ++k) { S += s_S[k]; SS += s_SS[k]; }
  const float invcnt = 1.0f / (float)(Bb * Nn * FD);
  const float mean = S * invcnt;
  const float var  = SS * invcnt - mean * mean;
  const float scale = gamma[c] * rsqrtf(var + 1e-5f);
  const float shift = beta[c] - mean * scale;

  if (tid < ROWS) {
    const unsigned long long m = maskbuf[blk];
    const float w = ((m >> tid) & 1ull) ? s_ws[2 * bmine] : s_ws[2 * bmine + 1];
    s_a[tid] = w * scale;
  }
  __syncthreads();

  const float4* __restrict__ h4 = (const float4*)(h + (size_t)bc * TILE) + seg * 2048;
  floatx4* __restrict__ o4 = (floatx4*)(out + (size_t)bc * TILE) + seg * 2048;
#pragma unroll
  for (int k = 0; k < 8; ++k) {
    const int idx = k * 256 + tid;
    const float a = s_a[idx >> 5];   // 32 float4 per row -> broadcast per 32 lanes
    float4 v = h4[idx];
    floatx4 r;
    r.x = fmaf(v.x, a, shift);
    r.y = fmaf(v.y, a, shift);
    r.z = fmaf(v.z, a, shift);
    r.w = fmaf(v.w, a, shift);
    r.x = r.x > 0.0f ? r.x : __expf(r.x) - 1.0f;
    r.y = r.y > 0.0f ? r.y : __expf(r.y) - 1.0f;
    r.z = r.z > 0.0f ? r.z : __expf(r.z) - 1.0f;
    r.w = r.w > 0.0f ? r.w : __expf(r.w) - 1.0f;
    __builtin_nontemporal_store(r, &o4[idx]);
  }
}

extern "C" void kernel_launch(void* const* d_in, const int* in_sizes, int n_in,
                              void* d_out, int out_size, void* d_ws, size_t ws_size,
                              hipStream_t stream) {
  const float* h     = (const float*)d_in[0];
  const float* op    = (const float*)d_in[1];
  const float* opS   = (const float*)d_in[2];
  const float* opQ   = (const float*)d_in[3];
  const float* gamma = (const float*)d_in[4];
  const float* beta  = (const float*)d_in[5];
  float* out = (float*)d_out;

  unsigned long long* maskbuf = (unsigned long long*)d_ws;   // 2048 u64 = 16 KB
  float* bpart = (float*)((char*)d_ws + 16384);              // 2048*8 floats = 64 KB

  s1<<<Bb * Cc * SEGS, 256, 0, stream>>>(h, op, opS, opQ, maskbuf, bpart);
  s2f<<<Bb * Cc * SEGS, 256, 0, stream>>>(h, maskbuf, bpart, gamma, beta, out);
}